// Round 1
// baseline (694.529 us; speedup 1.0000x reference)
//
#include <hip/hip_runtime.h>

static constexpr int KC   = 9;   // kernel bins
static constexpr int CIN  = 32;  // input channels
static constexpr int CA   = 24;  // branch-a out channels
static constexpr int CB   = 8;   // branch-b out channels
static constexpr int COUT = 32;  // CA + CB

// ---------------------------------------------------------------------------
// Kernel 1: CSR row pointer from sorted neighbors_out_index.
// row_ptr[n] = first edge with out index >= n; row_ptr[nout] = E.
// ---------------------------------------------------------------------------
__global__ void build_rowptr(const int* __restrict__ oidx, int* __restrict__ rp,
                             int E, int nout) {
    int e = blockIdx.x * blockDim.x + threadIdx.x;
    if (e >= E) return;
    int cur  = oidx[e];
    int prev = (e == 0) ? -1 : oidx[e - 1];
    for (int id = prev + 1; id <= cur; ++id) rp[id] = e;
    if (e == E - 1) {
        for (int id = cur + 1; id <= nout; ++id) rp[id] = E;
    }
}

// ---------------------------------------------------------------------------
// Kernel 2: pack W_a [9][32][24] and W_b [9][32][8] into W_cat [9][32][32]
// so the epilogue has one uniform, f-contiguous weight layout.
// ---------------------------------------------------------------------------
__global__ void pack_weights(const float* __restrict__ Wa,
                             const float* __restrict__ Wb,
                             float* __restrict__ Wc) {
    int t = blockIdx.x * blockDim.x + threadIdx.x;
    if (t >= KC * CIN * COUT) return;
    int f  = t & (COUT - 1);
    int kc = t >> 5;  // k*CIN + c
    Wc[t] = (f < CA) ? Wa[kc * CA + f] : Wb[kc * CB + (f - CA)];
}

// ---------------------------------------------------------------------------
// Kernel 3: fused edge accumulation + dual matmul epilogue.
// One wave (64 lanes) per output point; 4 waves per 256-thread block.
// Lane layout: c = lane&31 (channel), h = lane>>5 (half-wave; each half
// processes alternating edges). S tiles accumulated in LDS via ds_add_f32.
// ---------------------------------------------------------------------------
__global__ __launch_bounds__(256) void fused_conv(
    const float* __restrict__ feats, const float* __restrict__ importance,
    const float* __restrict__ Wc, const float* __restrict__ ba,
    const float* __restrict__ bb,
    const int* __restrict__ nidx, const int* __restrict__ nkidx,
    const int* __restrict__ rp,
    float* __restrict__ outf, float* __restrict__ outimp, int nout)
{
    __shared__ float sA[4][KC * CIN];
    __shared__ float sB[4][KC * CIN];

    const int wave = threadIdx.x >> 6;
    const int lane = threadIdx.x & 63;
    const int c    = lane & 31;
    const int h    = lane >> 5;
    const int n    = blockIdx.x * 4 + wave;

    // zero the per-wave S tiles
    {
        float* pA = &sA[0][0];
        float* pB = &sB[0][0];
        for (int i = threadIdx.x; i < 4 * KC * CIN; i += 256) {
            pA[i] = 0.f;
            pB[i] = 0.f;
        }
    }
    __syncthreads();

    int start = 0, end = 0;
    if (n < nout) { start = rp[n]; end = rp[n + 1]; }

    float accImp = 0.f;
    for (int e = start + h; e < end; e += 2) {
        int   idx = nidx[e];
        int   kk  = nkidx[e];
        float imp = importance[idx];
        float f   = feats[idx * CIN + c];   // coalesced 128B per half-wave
        accImp += imp;
        atomicAdd(&sA[wave][kk * CIN + c], f);        // ds_add_f32
        atomicAdd(&sB[wave][kk * CIN + c], f * imp);  // ds_add_f32
    }
    __syncthreads();
    if (n >= nout) return;

    // total importance over the segment (each lane of a half holds the same
    // per-half partial; combine the two halves)
    float impTot = accImp + __shfl_xor(accImp, 32, 64);
    float denom  = impTot > 0.f ? impTot : 1.f;

    // pull this lane's channel column of S into registers
    float acc1[KC], acc2[KC];
#pragma unroll
    for (int k = 0; k < KC; ++k) {
        float a = sA[wave][k * CIN + c];
        float b = sB[wave][k * CIN + c];
        acc1[k] = a;            // features h*16 + 0..7  (always branch-a)
        acc2[k] = h ? b : a;    // features h*16 + 8..15 (h1: 24..31 -> branch-b)
    }

    // partial products: p[j] = sum_k acc*W_cat[k][c][h*16+j]
    float p[16];
#pragma unroll
    for (int j = 0; j < 16; ++j) p[j] = 0.f;
#pragma unroll
    for (int k = 0; k < KC; ++k) {
        const float4* wp =
            reinterpret_cast<const float4*>(Wc + (k * CIN + c) * COUT + h * 16);
        float4 w0 = wp[0], w1 = wp[1], w2 = wp[2], w3 = wp[3];
        float a1 = acc1[k], a2 = acc2[k];
        p[0]  = fmaf(a1, w0.x, p[0]);  p[1]  = fmaf(a1, w0.y, p[1]);
        p[2]  = fmaf(a1, w0.z, p[2]);  p[3]  = fmaf(a1, w0.w, p[3]);
        p[4]  = fmaf(a1, w1.x, p[4]);  p[5]  = fmaf(a1, w1.y, p[5]);
        p[6]  = fmaf(a1, w1.z, p[6]);  p[7]  = fmaf(a1, w1.w, p[7]);
        p[8]  = fmaf(a2, w2.x, p[8]);  p[9]  = fmaf(a2, w2.y, p[9]);
        p[10] = fmaf(a2, w2.z, p[10]); p[11] = fmaf(a2, w2.w, p[11]);
        p[12] = fmaf(a2, w3.x, p[12]); p[13] = fmaf(a2, w3.y, p[13]);
        p[14] = fmaf(a2, w3.z, p[14]); p[15] = fmaf(a2, w3.w, p[15]);
    }

    // butterfly reduce over the 32 channel lanes within each half
#pragma unroll
    for (int m = 1; m <= 16; m <<= 1) {
#pragma unroll
        for (int j = 0; j < 16; ++j) p[j] += __shfl_xor(p[j], m, 64);
    }

    // lanes 0..15 of each half write features h*16 + 0..15
    if (c < 16) {
        int   f = h * 16 + c;
        float v = p[0];
#pragma unroll
        for (int j = 1; j < 16; ++j) v = (c == j) ? p[j] : v;
        float res;
        if (f < CA) res = v + ba[f];
        else        res = v / denom + bb[f - CA];
        outf[n * COUT + f] = fmaxf(res, 0.f);
    }
    if (lane == 0) outimp[n] = impTot;
}

// ---------------------------------------------------------------------------
extern "C" void kernel_launch(void* const* d_in, const int* in_sizes, int n_in,
                              void* d_out, int out_size, void* d_ws, size_t ws_size,
                              hipStream_t stream) {
    const float* feats      = (const float*)d_in[0];
    const float* importance = (const float*)d_in[1];
    const float* Wa         = (const float*)d_in[2];
    const float* ba         = (const float*)d_in[3];
    const float* Wb         = (const float*)d_in[4];
    const float* bb         = (const float*)d_in[5];
    const int*   nidx       = (const int*)d_in[6];
    const int*   nkidx      = (const int*)d_in[7];
    const int*   noidx      = (const int*)d_in[8];

    const int E    = in_sizes[6];
    const int nout = out_size / (COUT + 1);  // feats1 [nout][32] + out_imp [nout]

    float* outf   = (float*)d_out;
    float* outimp = outf + (size_t)nout * COUT;

    // workspace layout: row_ptr [(nout+1) ints] | W_cat [9*32*32 floats]
    int*   rp = (int*)d_ws;
    size_t rp_bytes = ((size_t)(nout + 1) * sizeof(int) + 255) & ~(size_t)255;
    float* Wc = (float*)((char*)d_ws + rp_bytes);

    build_rowptr<<<(E + 255) / 256, 256, 0, stream>>>(noidx, rp, E, nout);
    pack_weights<<<(KC * CIN * COUT + 255) / 256, 256, 0, stream>>>(Wa, Wb, Wc);
    fused_conv<<<(nout + 3) / 4, 256, 0, stream>>>(
        feats, importance, Wc, ba, bb, nidx, nkidx, rp, outf, outimp, nout);
}

// Round 2
// 609.446 us; speedup vs baseline: 1.1396x; 1.1396x over previous
//
#include <hip/hip_runtime.h>

static constexpr int KC   = 9;   // kernel bins
static constexpr int CIN  = 32;  // input channels
static constexpr int CA   = 24;  // branch-a out channels
static constexpr int CB   = 8;   // branch-b out channels
static constexpr int COUT = 32;  // CA + CB

// ---------------------------------------------------------------------------
// Kernel 1: CSR row pointer from sorted neighbors_out_index.
// ---------------------------------------------------------------------------
__global__ void build_rowptr(const int* __restrict__ oidx, int* __restrict__ rp,
                             int E, int nout) {
    int e = blockIdx.x * blockDim.x + threadIdx.x;
    if (e >= E) return;
    int cur  = oidx[e];
    int prev = (e == 0) ? -1 : oidx[e - 1];
    for (int id = prev + 1; id <= cur; ++id) rp[id] = e;
    if (e == E - 1) {
        for (int id = cur + 1; id <= nout; ++id) rp[id] = E;
    }
}

// ---------------------------------------------------------------------------
// Kernel 2: pack W_a [9][32][24] and W_b [9][32][8] into W_cat [9][32][32].
// ---------------------------------------------------------------------------
__global__ void pack_weights(const float* __restrict__ Wa,
                             const float* __restrict__ Wb,
                             float* __restrict__ Wc) {
    int t = blockIdx.x * blockDim.x + threadIdx.x;
    if (t >= KC * CIN * COUT) return;
    int f  = t & (COUT - 1);
    int kc = t >> 5;  // k*CIN + c
    Wc[t] = (f < CA) ? Wa[kc * CA + f] : Wb[kc * CB + (f - CA)];
}

// ---------------------------------------------------------------------------
// Kernel 3: fused edge accumulation + dual matmul epilogue.
// One wave per output point; 4 waves per block.
// Edge loop v2: cooperative 64-edge metadata preload (incl. importance
// gather, 1 lane per edge) into per-wave LDS, then 4-edge-unrolled feats
// gather per half-wave for 4-way MLP.
// ---------------------------------------------------------------------------
__global__ __launch_bounds__(256) void fused_conv(
    const float* __restrict__ feats, const float* __restrict__ importance,
    const float* __restrict__ Wc, const float* __restrict__ ba,
    const float* __restrict__ bb,
    const int* __restrict__ nidx, const int* __restrict__ nkidx,
    const int* __restrict__ rp,
    float* __restrict__ outf, float* __restrict__ outimp, int nout)
{
    __shared__ float sA[4][KC * CIN];
    __shared__ float sB[4][KC * CIN];
    __shared__ int   sIdx[4][64];
    __shared__ int   sKk [4][64];
    __shared__ float sImp[4][64];

    const int wave = threadIdx.x >> 6;
    const int lane = threadIdx.x & 63;
    const int c    = lane & 31;
    const int h    = lane >> 5;
    const int n    = blockIdx.x * 4 + wave;

    // zero the per-wave S tiles (all threads zero all tiles -> barrier once)
    {
        float* pA = &sA[0][0];
        float* pB = &sB[0][0];
        for (int i = threadIdx.x; i < 4 * KC * CIN; i += 256) {
            pA[i] = 0.f;
            pB[i] = 0.f;
        }
    }
    __syncthreads();

    int start = 0, end = 0;
    if (n < nout) { start = rp[n]; end = rp[n + 1]; }

    float accImp = 0.f;
    for (int base = start; base < end; base += 64) {
        int cnt = end - base; if (cnt > 64) cnt = 64;

        // cooperative metadata load: lane j <-> edge base+j
        int idxv = 0, kkv = 0; float impv = 0.f;
        if (lane < cnt) {
            int j = base + lane;
            idxv = nidx[j];
            kkv  = nkidx[j];
            impv = importance[idxv];   // one gather per edge (was 32)
        }
        accImp += impv;
        sIdx[wave][lane] = idxv;
        sKk [wave][lane] = kkv;
        sImp[wave][lane] = impv;
        // same-wave LDS RAW: compiler inserts lgkmcnt waits, no barrier needed

        int t = h;
        // main loop: 4 edges per half-wave per iteration (8/wave)
        for (; t + 6 < cnt; t += 8) {
            int   i0 = sIdx[wave][t],     i1 = sIdx[wave][t + 2];
            int   i2 = sIdx[wave][t + 4], i3 = sIdx[wave][t + 6];
            int   k0 = sKk[wave][t],      k1 = sKk[wave][t + 2];
            int   k2 = sKk[wave][t + 4],  k3 = sKk[wave][t + 6];
            float m0 = sImp[wave][t],     m1 = sImp[wave][t + 2];
            float m2 = sImp[wave][t + 4], m3 = sImp[wave][t + 6];
            // 4 independent coalesced row gathers in flight
            float f0 = feats[(size_t)i0 * CIN + c];
            float f1 = feats[(size_t)i1 * CIN + c];
            float f2 = feats[(size_t)i2 * CIN + c];
            float f3 = feats[(size_t)i3 * CIN + c];
            atomicAdd(&sA[wave][k0 * CIN + c], f0);
            atomicAdd(&sB[wave][k0 * CIN + c], f0 * m0);
            atomicAdd(&sA[wave][k1 * CIN + c], f1);
            atomicAdd(&sB[wave][k1 * CIN + c], f1 * m1);
            atomicAdd(&sA[wave][k2 * CIN + c], f2);
            atomicAdd(&sB[wave][k2 * CIN + c], f2 * m2);
            atomicAdd(&sA[wave][k3 * CIN + c], f3);
            atomicAdd(&sB[wave][k3 * CIN + c], f3 * m3);
        }
        // tail
        for (; t < cnt; t += 2) {
            int   i0 = sIdx[wave][t];
            int   k0 = sKk[wave][t];
            float m0 = sImp[wave][t];
            float f0 = feats[(size_t)i0 * CIN + c];
            atomicAdd(&sA[wave][k0 * CIN + c], f0);
            atomicAdd(&sB[wave][k0 * CIN + c], f0 * m0);
        }
    }
    if (n >= nout) return;

    // total importance: each lane holds distinct edges' sum -> reduce 64 lanes
    float impTot = accImp;
#pragma unroll
    for (int m = 1; m < 64; m <<= 1) impTot += __shfl_xor(impTot, m, 64);
    float denom = impTot > 0.f ? impTot : 1.f;

    // pull this lane's channel column of S into registers
    float acc1[KC], acc2[KC];
#pragma unroll
    for (int k = 0; k < KC; ++k) {
        float a = sA[wave][k * CIN + c];
        float b = sB[wave][k * CIN + c];
        acc1[k] = a;            // features h*16 + 0..7  (always branch-a)
        acc2[k] = h ? b : a;    // features h*16 + 8..15 (h1: 24..31 -> branch-b)
    }

    // partial products: p[j] = sum_k acc*W_cat[k][c][h*16+j]
    float p[16];
#pragma unroll
    for (int j = 0; j < 16; ++j) p[j] = 0.f;
#pragma unroll
    for (int k = 0; k < KC; ++k) {
        const float4* wp =
            reinterpret_cast<const float4*>(Wc + (k * CIN + c) * COUT + h * 16);
        float4 w0 = wp[0], w1 = wp[1], w2 = wp[2], w3 = wp[3];
        float a1 = acc1[k], a2 = acc2[k];
        p[0]  = fmaf(a1, w0.x, p[0]);  p[1]  = fmaf(a1, w0.y, p[1]);
        p[2]  = fmaf(a1, w0.z, p[2]);  p[3]  = fmaf(a1, w0.w, p[3]);
        p[4]  = fmaf(a1, w1.x, p[4]);  p[5]  = fmaf(a1, w1.y, p[5]);
        p[6]  = fmaf(a1, w1.z, p[6]);  p[7]  = fmaf(a1, w1.w, p[7]);
        p[8]  = fmaf(a2, w2.x, p[8]);  p[9]  = fmaf(a2, w2.y, p[9]);
        p[10] = fmaf(a2, w2.z, p[10]); p[11] = fmaf(a2, w2.w, p[11]);
        p[12] = fmaf(a2, w3.x, p[12]); p[13] = fmaf(a2, w3.y, p[13]);
        p[14] = fmaf(a2, w3.z, p[14]); p[15] = fmaf(a2, w3.w, p[15]);
    }

    // fold-and-halve transpose reduce: 16 values over 32 channel lanes.
    // At step s (mask 2^s), keep values whose bit s matches lane bit s.
    const int b0 = c & 1, b1 = (c >> 1) & 1, b2 = (c >> 2) & 1, b3 = (c >> 3) & 1;
    float v8[8];
#pragma unroll
    for (int q = 0; q < 8; ++q) {
        float kept = b0 ? p[2 * q + 1] : p[2 * q];
        float giv  = b0 ? p[2 * q]     : p[2 * q + 1];
        v8[q] = kept + __shfl_xor(giv, 1, 64);
    }
    float v4[4];
#pragma unroll
    for (int q = 0; q < 4; ++q) {
        float kept = b1 ? v8[2 * q + 1] : v8[2 * q];
        float giv  = b1 ? v8[2 * q]     : v8[2 * q + 1];
        v4[q] = kept + __shfl_xor(giv, 2, 64);
    }
    float v2[2];
#pragma unroll
    for (int q = 0; q < 2; ++q) {
        float kept = b2 ? v4[2 * q + 1] : v4[2 * q];
        float giv  = b2 ? v4[2 * q]     : v4[2 * q + 1];
        v2[q] = kept + __shfl_xor(giv, 4, 64);
    }
    float kept = b3 ? v2[1] : v2[0];
    float giv  = b3 ? v2[0] : v2[1];
    float v1 = kept + __shfl_xor(giv, 8, 64);
    v1 += __shfl_xor(v1, 16, 64);
    // now lane c holds the full sum for feature index (c & 15) of its half

    if (c < 16) {
        int   f = h * 16 + c;
        float res;
        if (f < CA) res = v1 + ba[f];
        else        res = v1 / denom + bb[f - CA];
        outf[n * COUT + f] = fmaxf(res, 0.f);
    }
    if (lane == 0) outimp[n] = impTot;
}

// ---------------------------------------------------------------------------
extern "C" void kernel_launch(void* const* d_in, const int* in_sizes, int n_in,
                              void* d_out, int out_size, void* d_ws, size_t ws_size,
                              hipStream_t stream) {
    const float* feats      = (const float*)d_in[0];
    const float* importance = (const float*)d_in[1];
    const float* Wa         = (const float*)d_in[2];
    const float* ba         = (const float*)d_in[3];
    const float* Wb         = (const float*)d_in[4];
    const float* bb         = (const float*)d_in[5];
    const int*   nidx       = (const int*)d_in[6];
    const int*   nkidx      = (const int*)d_in[7];
    const int*   noidx      = (const int*)d_in[8];

    const int E    = in_sizes[6];
    const int nout = out_size / (COUT + 1);

    float* outf   = (float*)d_out;
    float* outimp = outf + (size_t)nout * COUT;

    int*   rp = (int*)d_ws;
    size_t rp_bytes = ((size_t)(nout + 1) * sizeof(int) + 255) & ~(size_t)255;
    float* Wc = (float*)((char*)d_ws + rp_bytes);

    build_rowptr<<<(E + 255) / 256, 256, 0, stream>>>(noidx, rp, E, nout);
    pack_weights<<<(KC * CIN * COUT + 255) / 256, 256, 0, stream>>>(Wa, Wb, Wc);
    fused_conv<<<(nout + 3) / 4, 256, 0, stream>>>(
        feats, importance, Wc, ba, bb, nidx, nkidx, rp, outf, outimp, nout);
}